// Round 9
// baseline (358.481 us; speedup 1.0000x reference)
//
#include <hip/hip_runtime.h>
#include <cstdint>
#include <cstddef>

typedef __attribute__((ext_vector_type(8))) __bf16 bf16x8;
typedef __attribute__((ext_vector_type(4))) float f32x4;

#define MFMA16(a, b, c) __builtin_amdgcn_mfma_f32_16x16x32_bf16((a), (b), (c), 0, 0, 0)

__device__ __forceinline__ float fast_tanh(float z) {
    float e = __expf(2.0f * z);
    return 1.0f - 2.0f * __builtin_amdgcn_rcpf(e + 1.0f);
}
__device__ __forceinline__ float fast_sigmoid(float z) {
    return __builtin_amdgcn_rcpf(1.0f + __expf(-z));
}

// Guaranteed global (AS1) vector load -> global_load_dwordx4, vmcnt-only.
__device__ __forceinline__ f32x4 gload4(const float* p) {
    return *(const __attribute__((address_space(1))) f32x4*)p;
}

__device__ __forceinline__ unsigned pk2(float a, float b) {
    union { __bf16 h[2]; unsigned u; } p;
    p.h[0] = (__bf16)a;
    p.h[1] = (__bf16)b;
    return p.u;
}

__device__ __forceinline__ bf16x8 cvt8(f32x4 a, f32x4 b) {
    bf16x8 f;
    f[0] = (__bf16)a[0]; f[1] = (__bf16)a[1]; f[2] = (__bf16)a[2]; f[3] = (__bf16)a[3];
    f[4] = (__bf16)b[0]; f[5] = (__bf16)b[1]; f[6] = (__bf16)b[2]; f[7] = (__bf16)b[3];
    return f;
}

// weight A-fragment: lane holds row `row`, k = k0..k0+7 (row-major W[64][64])
__device__ __forceinline__ bf16x8 ldwfrag(const float* __restrict__ W, int row, int k0) {
    const f32x4 a = *(const f32x4*)(W + row * 64 + k0);
    const f32x4 b = *(const f32x4*)(W + row * 64 + k0 + 4);
    return cvt8(a, b);
}

// Cox-de Boor, order 3, 12 knots -> 8 basis funcs (exact reference replication).
__device__ __forceinline__ void bspl8(float x, const float* kn, float* B) {
    float b[11];
#pragma unroll
    for (int m = 0; m < 11; ++m)
        b[m] = (x >= kn[m] && x < kn[m + 1]) ? 1.0f : 0.0f;
#pragma unroll
    for (int d = 1; d <= 3; ++d) {
#pragma unroll
        for (int m = 0; m + d < 11; ++m) {
            float lf = (x - kn[m]) / (kn[m + d] - kn[m]) * b[m];
            float rt = (kn[m + d + 1] - x) / (kn[m + d + 1] - kn[m + 1]) * b[m + 1];
            b[m] = lf + rt;
        }
    }
#pragma unroll
    for (int m = 0; m < 8; ++m) B[m] = b[m];
}

// Wave-specialized pipeline. One block = 16 samples, 12 waves (768 thr), one
// barrier/step. Under "MFMA blocks its wave", the serial recurrences keep only
// 2 MFMAs each:
//   GX (waves 0-3,  rt=wv&3): xz(t+1)=b0+Wih0@x(t+1); p2=b1+Wih1@h1(t-1) -> f32 LDS
//   G1 (waves 4-7):  h1(t) = tanh(xz(t) + Whh0@h1(t-1))        [2 MFMA]
//   G2 (waves 8-11): h2(t-2) = tanh(p2 + Whh1@h2(t-3))         [2 MFMA, skew 2]
__global__ __launch_bounds__(768) void rnn_kan_v8(
    const float* __restrict__ x,
    const float* __restrict__ wih0, const float* __restrict__ whh0,
    const float* __restrict__ bih0, const float* __restrict__ bhh0,
    const float* __restrict__ wih1, const float* __restrict__ whh1,
    const float* __restrict__ bih1, const float* __restrict__ bhh1,
    const float* __restrict__ grid0, const float* __restrict__ coef0,
    const float* __restrict__ sb0, const float* __restrict__ sp0,
    const float* __restrict__ grid1, const float* __restrict__ coef1,
    const float* __restrict__ sb1, const float* __restrict__ sp1,
    float* __restrict__ out)
{
    __shared__ __align__(16) float s_xz[2][16 * 64];      // xz(t) at parity t&1 (f32, swizzled)
    __shared__ __align__(16) float s_p2[2][16 * 64];      // p2 written at t -> parity t&1
    __shared__ __align__(16) unsigned char s_h1[2][2048]; // h1(t) bf16 at parity t&1
    __shared__ __align__(16) unsigned char s_h2[2][2048]; // h2(tau) bf16 at parity tau&1
    __shared__ __align__(16) float s_hf[16][68];          // final h2 fp32
    __shared__ __align__(16) float s_bas[1024][12];       // KAN0 basis[8] + silu at [8]
    __shared__ __align__(16) float s_e[16][17];           // KAN1 edge values

    const int tid  = threadIdx.x;
    const int wv   = tid >> 6;
    const int lane = tid & 63;
    const int sc   = lane & 15;   // MFMA col (= sample)
    const int gr   = lane >> 4;   // 16-lane group
    const int role = wv >> 2;     // 0=GX, 1=G1, 2=G2
    const int rt   = wv & 3;      // row-tile (rows 16rt..16rt+15)
    const int s0   = blockIdx.x << 4;

    // ---- LDS byte offsets (XOR-swizzle keeps 16B alignment, 2-way max conflict)
    const unsigned swz  = (unsigned)(sc & 7) << 4;
    const unsigned offW  = sc * 128 + (((unsigned)(32 * rt + 8 * gr)) ^ swz);  // bf16 h write (b64)
    const unsigned offR0 = sc * 128 + (((unsigned)(16 * gr)) ^ swz);           // h B-frag kt0 (b128)
    const unsigned offR1 = sc * 128 + (((unsigned)(64 + 16 * gr)) ^ swz);      // h B-frag kt1
    const unsigned offX  = sc * 256 + (((unsigned)(64 * rt + 16 * gr)) ^ swz); // f32x4 C rows (b128)

    // ---- zero initial state: h1(-1)=0 (buf1), h2 zeros (both bufs)
    for (int i = tid; i < 512; i += 768) ((unsigned*)&s_h1[1][0])[i] = 0u;
    for (int i = tid; i < 1024; i += 768) ((unsigned*)&s_h2[0][0])[i] = 0u;

    // ---- per-role weights/biases
    bf16x8 fA0, fA1, fB0, fB1;
    f32x4 b0a, b1a;
    const float* xb = x + (size_t)(s0 + sc) * 16384 + 8 * gr;  // GX only
    f32x4 r0[2], r1[2], r2[2], r3[2];                          // GX x ring (x(t+1) at slot (t+1)&1)

    if (role == 0) {
        fA0 = ldwfrag(wih0, 16 * rt + sc, 8 * gr);
        fA1 = ldwfrag(wih0, 16 * rt + sc, 32 + 8 * gr);
        fB0 = ldwfrag(wih1, 16 * rt + sc, 8 * gr);
        fB1 = ldwfrag(wih1, 16 * rt + sc, 32 + 8 * gr);
#pragma unroll
        for (int i = 0; i < 4; ++i) {
            const int h = 16 * rt + 4 * gr + i;
            b0a[i] = bih0[h] + bhh0[h];
            b1a[i] = bih1[h] + bhh1[h];
        }
        // x(0) direct; ring: x(1)->slot1, x(2)->slot0
        f32x4 q0 = gload4(xb),      q1 = gload4(xb + 4);
        f32x4 q2 = gload4(xb + 32), q3 = gload4(xb + 36);
        r0[1] = gload4(xb + 64);  r1[1] = gload4(xb + 68);
        r2[1] = gload4(xb + 96);  r3[1] = gload4(xb + 100);
        r0[0] = gload4(xb + 128); r1[0] = gload4(xb + 132);
        r2[0] = gload4(xb + 160); r3[0] = gload4(xb + 164);
        // xz(0) -> s_xz[0]
        f32x4 a = MFMA16(fA0, cvt8(q0, q1), b0a);
        a = MFMA16(fA1, cvt8(q2, q3), a);
        *(f32x4*)((char*)&s_xz[0][0] + offX) = a;
    } else if (role == 1) {
        fA0 = ldwfrag(whh0, 16 * rt + sc, 8 * gr);
        fA1 = ldwfrag(whh0, 16 * rt + sc, 32 + 8 * gr);
    } else {
        fA0 = ldwfrag(whh1, 16 * rt + sc, 8 * gr);
        fA1 = ldwfrag(whh1, 16 * rt + sc, 32 + 8 * gr);
    }
    __syncthreads();

    // ---- main loop: one barrier per step, t = 0..257 (epilogue folded in)
    for (int t = 0; t < 258; ++t) {
        const int par = t & 1;
        if (role == 0) {
            if (t < 255) {  // xz(t+1) from ring slot par^1; refill with x(t+3)
                bf16x8 xf0 = cvt8(r0[par ^ 1], r1[par ^ 1]);
                bf16x8 xf1 = cvt8(r2[par ^ 1], r3[par ^ 1]);
                const float* pn = xb + (size_t)((t + 3 > 255) ? 255 : t + 3) * 64;
                r0[par ^ 1] = gload4(pn);      r1[par ^ 1] = gload4(pn + 4);
                r2[par ^ 1] = gload4(pn + 32); r3[par ^ 1] = gload4(pn + 36);
                f32x4 a = MFMA16(fA0, xf0, b0a);
                a = MFMA16(fA1, xf1, a);
                *(f32x4*)((char*)&s_xz[par ^ 1][0] + offX) = a;
            }
            if (t <= 256) {  // p2 = b1 + Wih1 @ h1(t-1) -> s_p2[t&1]
                bf16x8 h1f0 = *(const bf16x8*)((const char*)&s_h1[par ^ 1][0] + offR0);
                bf16x8 h1f1 = *(const bf16x8*)((const char*)&s_h1[par ^ 1][0] + offR1);
                f32x4 p = MFMA16(fB0, h1f0, b1a);
                p = MFMA16(fB1, h1f1, p);
                *(f32x4*)((char*)&s_p2[par][0] + offX) = p;
            }
        } else if (role == 1) {
            if (t <= 255) {  // h1(t) = tanh(xz(t) + Whh0 @ h1(t-1))
                f32x4 xzf = *(const f32x4*)((const char*)&s_xz[par][0] + offX);
                bf16x8 h1f0 = *(const bf16x8*)((const char*)&s_h1[par ^ 1][0] + offR0);
                bf16x8 h1f1 = *(const bf16x8*)((const char*)&s_h1[par ^ 1][0] + offR1);
                f32x4 z = MFMA16(fA0, h1f0, xzf);
                z = MFMA16(fA1, h1f1, z);
                float v[4];
#pragma unroll
                for (int i = 0; i < 4; ++i) v[i] = fast_tanh(z[i]);
                uint2 pw; pw.x = pk2(v[0], v[1]); pw.y = pk2(v[2], v[3]);
                *(uint2*)((char*)&s_h1[par][0] + offW) = pw;
            }
        } else {
            if (t >= 2) {    // h2(t-2) = tanh(p2 + Whh1 @ h2(t-3))
                f32x4 p2f = *(const f32x4*)((const char*)&s_p2[par ^ 1][0] + offX);
                bf16x8 h2f0 = *(const bf16x8*)((const char*)&s_h2[par ^ 1][0] + offR0);
                bf16x8 h2f1 = *(const bf16x8*)((const char*)&s_h2[par ^ 1][0] + offR1);
                f32x4 z = MFMA16(fA0, h2f0, p2f);
                z = MFMA16(fA1, h2f1, z);
                float v[4];
#pragma unroll
                for (int i = 0; i < 4; ++i) v[i] = fast_tanh(z[i]);
                if (t <= 256) {
                    uint2 pw; pw.x = pk2(v[0], v[1]); pw.y = pk2(v[2], v[3]);
                    *(uint2*)((char*)&s_h2[par][0] + offW) = pw;
                } else {     // t == 257: h2(255) -> fp32 for KAN
                    f32x4 hv;
#pragma unroll
                    for (int i = 0; i < 4; ++i) hv[i] = v[i];
                    *(f32x4*)(&s_hf[sc][16 * rt + 4 * gr]) = hv;
                }
            }
        }
        asm volatile("s_waitcnt lgkmcnt(0)" ::: "memory");
        __builtin_amdgcn_s_barrier();
        asm volatile("" ::: "memory");
    }

    // ---- KAN epilogue (768 threads, 16 samples)
    float kn0[12], kn1[12];
#pragma unroll
    for (int m = 0; m < 12; ++m) { kn0[m] = grid0[m]; kn1[m] = grid1[m]; }

    for (int q = tid; q < 1024; q += 768) {
        const int i = q >> 4, s = q & 15;
        const float v = s_hf[s][i];
        float B[8];
        bspl8(v, kn0, B);
        *(float4*)(&s_bas[q][0]) = make_float4(B[0], B[1], B[2], B[3]);
        *(float4*)(&s_bas[q][4]) = make_float4(B[4], B[5], B[6], B[7]);
        s_bas[q][8] = v * fast_sigmoid(v);
    }
    __syncthreads();

    if (tid < 256) {
        const int s = tid >> 4, o = tid & 15;
        float acc = 0.0f;
        for (int i = 0; i < 64; ++i) {
            const int q = (i << 4) + s;
            const float4 B0 = *(const float4*)(&s_bas[q][0]);
            const float4 B1 = *(const float4*)(&s_bas[q][4]);
            const float sil = s_bas[q][8];
            const float* cp = coef0 + i * 128 + o * 8;
            const float4 c0 = *(const float4*)cp;
            const float4 c1 = *(const float4*)(cp + 4);
            const float spl = B0.x * c0.x + B0.y * c0.y + B0.z * c0.z + B0.w * c0.w +
                              B1.x * c1.x + B1.y * c1.y + B1.z * c1.z + B1.w * c1.w;
            acc += sil * sb0[(i << 4) + o] + sp0[(i << 4) + o] * spl;
        }
        float B[8];
        bspl8(acc, kn1, B);
        const float* cp = coef1 + o * 8;
        float spl = 0.0f;
#pragma unroll
        for (int k = 0; k < 8; ++k) spl += B[k] * cp[k];
        s_e[s][o] = (acc * fast_sigmoid(acc)) * sb1[o] + sp1[o] * spl;
    }
    __syncthreads();

    if (tid < 16) {
        float sum = 0.0f;
#pragma unroll
        for (int o = 0; o < 16; ++o) sum += s_e[tid][o];
        out[s0 + tid] = fast_sigmoid(sum);
    }
}

extern "C" void kernel_launch(void* const* d_in, const int* in_sizes, int n_in,
                              void* d_out, int out_size, void* d_ws, size_t ws_size,
                              hipStream_t stream) {
    (void)n_in; (void)out_size; (void)d_ws; (void)ws_size;
    const int B = in_sizes[0] / (256 * 64);   // 2048
    const int grid = B / 16;                  // 128 blocks of 16 samples
    rnn_kan_v8<<<dim3(grid), dim3(768), 0, stream>>>(
        (const float*)d_in[0],
        (const float*)d_in[1], (const float*)d_in[2], (const float*)d_in[3], (const float*)d_in[4],
        (const float*)d_in[5], (const float*)d_in[6], (const float*)d_in[7], (const float*)d_in[8],
        (const float*)d_in[9], (const float*)d_in[10], (const float*)d_in[11], (const float*)d_in[12],
        (const float*)d_in[13], (const float*)d_in[14], (const float*)d_in[15], (const float*)d_in[16],
        (float*)d_out);
}